// Round 11
// baseline (314.644 us; speedup 1.0000x reference)
//
#include <hip/hip_runtime.h>
#include <hip/hip_bf16.h>

#define TOKENS 4096
#define DMODEL 768
#define DHID   3072
#define NEXP   8
#define MAXT   72     // sum ceil(ce/128) <= 8192/128 + 7 = 71

typedef __bf16 bf16x8 __attribute__((ext_vector_type(8)));
typedef float  f32x4  __attribute__((ext_vector_type(4)));
typedef unsigned short ushort_t;

#define VMCNT(n) asm volatile("s_waitcnt vmcnt(" #n ")" ::: "memory")

__device__ __forceinline__ void wg_barrier() {
    asm volatile("" ::: "memory");
    __builtin_amdgcn_s_barrier();
    asm volatile("" ::: "memory");
}

__device__ __forceinline__ float gelu_tanh(float x) {
    // jax.nn.gelu default (approximate=True)
    float z = 0.7978845608028654f * (x + 0.044715f * x * x * x);
    float t = 1.0f - 2.0f / (__expf(2.0f * z) + 1.0f);
    return 0.5f * x * (1.0f + t);
}

__device__ __forceinline__ float bf2f(ushort_t u) {
    unsigned v = ((unsigned)u) << 16;
    return __builtin_bit_cast(float, v);
}

__device__ __forceinline__ void gload16(const void* g, void* l) {
    __builtin_amdgcn_global_load_lds((const __attribute__((address_space(1))) void*)g,
                                     (__attribute__((address_space(3))) void*)l, 16, 0, 0);
}

// ---------------- transpose + convert: in fp32 [R][C] -> out bf16 [C][R] ----------------
__global__ void k_transpose_cvt(const float* __restrict__ in, ushort_t* __restrict__ out,
                                int R, int C) {
    __shared__ float tile[64 * 68];
    const int bx = blockIdx.x, by = blockIdx.y, bz = blockIdx.z;
    const float* ip = in + (size_t)bz * R * C;
    ushort_t* op = out + (size_t)bz * R * C;
    const int tid = threadIdx.x;
    {
        const int cq = tid & 15, rg = tid >> 4;
#pragma unroll
        for (int i = 0; i < 4; ++i) {
            int rl = rg + i * 16;
            float4 v = *(const float4*)(ip + (size_t)(by * 64 + rl) * C + bx * 64 + cq * 4);
            *(float4*)(&tile[rl * 68 + cq * 4]) = v;
        }
    }
    __syncthreads();
    {
        const int rq = tid & 15, cg = tid >> 4;
#pragma unroll
        for (int i = 0; i < 4; ++i) {
            int cl = cg + i * 16;
            ushort4 o;
            o.x = __builtin_bit_cast(ushort_t, (__bf16)tile[(rq * 4 + 0) * 68 + cl]);
            o.y = __builtin_bit_cast(ushort_t, (__bf16)tile[(rq * 4 + 1) * 68 + cl]);
            o.z = __builtin_bit_cast(ushort_t, (__bf16)tile[(rq * 4 + 2) * 68 + cl]);
            o.w = __builtin_bit_cast(ushort_t, (__bf16)tile[(rq * 4 + 3) * 68 + cl]);
            *(ushort4*)(op + (size_t)(bx * 64 + cl) * R + by * 64 + rq * 4) = o;
        }
    }
}

// ---------------- router: LDS-transposed Wr, 8 tokens/wave, block-aggregated atomics ----------------
__launch_bounds__(256)
__global__ void k_router(const float* __restrict__ x, const float* __restrict__ Wr,
                         const float* __restrict__ br, int* __restrict__ cnt,
                         int* __restrict__ tok, int* __restrict__ slot,
                         float* __restrict__ wslot, ushort_t* __restrict__ xb) {
    __shared__ float WrT[NEXP * DMODEL];
    __shared__ int   te0[32], te1[32];
    __shared__ int   lcnt[NEXP], gbase[NEXP];

    const int tid = threadIdx.x;
    const int wv = tid >> 6, lane = tid & 63;

#pragma unroll
    for (int i = 0; i < 6; ++i) {
        int idx4 = i * 256 + tid;
        float4 v = ((const float4*)Wr)[idx4];
        int flat = idx4 * 4;
        int d = flat >> 3, e0 = flat & 7;
        WrT[(e0 + 0) * DMODEL + d] = v.x;
        WrT[(e0 + 1) * DMODEL + d] = v.y;
        WrT[(e0 + 2) * DMODEL + d] = v.z;
        WrT[(e0 + 3) * DMODEL + d] = v.w;
    }
    if (tid < NEXP) lcnt[tid] = 0;
    float brv[8];
#pragma unroll
    for (int e = 0; e < 8; ++e) brv[e] = br[e];
    __syncthreads();

#pragma unroll 1
    for (int it = 0; it < 8; ++it) {
        int t = blockIdx.x * 32 + wv * 8 + it;
        const float* xr = x + (size_t)t * DMODEL;
        float4 xv[3];
#pragma unroll
        for (int j = 0; j < 3; ++j) xv[j] = *(const float4*)(xr + (j * 64 + lane) * 4);
#pragma unroll
        for (int j = 0; j < 3; ++j) {
            int base = (j * 64 + lane) * 4;
            ushort4 o;
            o.x = __builtin_bit_cast(ushort_t, (__bf16)xv[j].x);
            o.y = __builtin_bit_cast(ushort_t, (__bf16)xv[j].y);
            o.z = __builtin_bit_cast(ushort_t, (__bf16)xv[j].z);
            o.w = __builtin_bit_cast(ushort_t, (__bf16)xv[j].w);
            *(ushort4*)(xb + (size_t)t * DMODEL + base) = o;
        }
        float lg[8];
#pragma unroll
        for (int e = 0; e < 8; ++e) {
            float s = 0.f;
#pragma unroll
            for (int j = 0; j < 3; ++j) {
                const float4 wv4 = *(const float4*)(&WrT[e * DMODEL + (j * 64 + lane) * 4]);
                s += xv[j].x * wv4.x;
                s += xv[j].y * wv4.y;
                s += xv[j].z * wv4.z;
                s += xv[j].w * wv4.w;
            }
#pragma unroll
            for (int o = 32; o > 0; o >>= 1) s += __shfl_xor(s, o);
            lg[e] = s + brv[e];
        }
        if (lane == 0) {
            int e0 = 0; float b0 = lg[0];
#pragma unroll
            for (int e = 1; e < 8; ++e) if (lg[e] > b0) { b0 = lg[e]; e0 = e; }
            int e1 = -1; float b1v = -1e30f;
#pragma unroll
            for (int e = 0; e < 8; ++e) if (e != e0 && lg[e] > b1v) { b1v = lg[e]; e1 = e; }
            float w0 = 1.f / (1.f + __expf(b1v - b0));
            float w1 = 1.f - w0;
            int lt = wv * 8 + it;
            te0[lt] = e0; te1[lt] = e1;
            wslot[2 * t] = w0; wslot[2 * t + 1] = w1;
        }
    }
    __syncthreads();

    int myE = 0, myPos = 0, myTok = 0, myK = 0;
    if (tid < 64) {
        int lt = tid >> 1; myK = tid & 1;
        myE = myK ? te1[lt] : te0[lt];
        myTok = blockIdx.x * 32 + lt;
        myPos = atomicAdd(&lcnt[myE], 1);
    }
    __syncthreads();
    if (tid < NEXP) gbase[tid] = atomicAdd(&cnt[tid], lcnt[tid]);
    __syncthreads();
    if (tid < 64) {
        int g = gbase[myE] + myPos;
        tok[myE * TOKENS + g] = myTok;
        slot[myE * TOKENS + g] = 2 * myTok + myK;
    }
}

// ---------------- tile scheduler: single BM=128 table ----------------
__global__ void k_sched(const int* __restrict__ cnt, int* __restrict__ sch) {
    if (threadIdx.x == 0) {
        int base = 0, n = 0;
        for (int e = 0; e < NEXP; ++e) {
            sch[2 + e] = base;
            int ce = cnt[e];
            for (int m = 0; m < ce; m += 128) sch[16 + n++] = (e << 20) | m;
            base += ce;
        }
        sch[0] = n;
    }
}

// ---------------- 128x128 GEMM: A direct global->VGPR (reg dbuf), B in swizzled LDS ----
// 4 waves (2x2), wave 64x64, BK=64, B dbuf 2x16KB, 1 VMCNT(0)+barrier per K-tile,
// 2 blocks/CU. A-frag: lane(fr,fg) reads A[row=...+fr][k=kt*64+ks*32+fg*8] as bf16x8
// (16 full 64B lines per wave-load, no amplification; rows gathered via tok for stage A).
// B LDS region (per ks, 8KB): row(col)*64B + ((blk^((row>>1)&3))<<4) swizzle.

#define BODY(kt_, AC, AN)                                                              \
    {                                                                                  \
        char* bufc = ldsB + ((kt_) & 1) * 16384;                                       \
        if ((kt_) + 1 < NT) {                                                          \
            char* bufn = ldsB + (((kt_) + 1) & 1) * 16384;                             \
            _Pragma("unroll")                                                          \
            for (int i_ = 0; i_ < 4; ++i_)                                             \
                gload16(bSrc[i_] + ((kt_) + 1) * 64, bufn + bDst[i_]);                 \
            _Pragma("unroll")                                                          \
            for (int mi_ = 0; mi_ < 4; ++mi_) {                                        \
                AN[mi_]     = *(const bf16x8*)(aRowP[mi_] + ((kt_) + 1) * 64);         \
                AN[4 + mi_] = *(const bf16x8*)(aRowP[mi_] + ((kt_) + 1) * 64 + 32);    \
            }                                                                          \
        }                                                                              \
        bf16x8 bf0[4], bf1[4];                                                         \
        _Pragma("unroll")                                                              \
        for (int ni_ = 0; ni_ < 4; ++ni_) {                                            \
            bf0[ni_] = *(const bf16x8*)(bufc + bOff[ni_]);                             \
            bf1[ni_] = *(const bf16x8*)(bufc + 8192 + bOff[ni_]);                      \
        }                                                                              \
        __builtin_amdgcn_s_setprio(1);                                                 \
        _Pragma("unroll")                                                              \
        for (int mi_ = 0; mi_ < 4; ++mi_) {                                            \
            _Pragma("unroll")                                                          \
            for (int ni_ = 0; ni_ < 4; ++ni_) {                                        \
                acc[mi_][ni_] = __builtin_amdgcn_mfma_f32_16x16x32_bf16(AC[mi_], bf0[ni_], acc[mi_][ni_], 0, 0, 0); \
                acc[mi_][ni_] = __builtin_amdgcn_mfma_f32_16x16x32_bf16(AC[4 + mi_], bf1[ni_], acc[mi_][ni_], 0, 0, 0); \
            }                                                                          \
        }                                                                              \
        __builtin_amdgcn_s_setprio(0);                                                 \
        VMCNT(0);                                                                      \
        wg_barrier();                                                                  \
    }

template<bool STAGE1>
__launch_bounds__(256, 2)
__global__ void k_gemm8(const ushort_t* __restrict__ Abase, const int* __restrict__ tok,
                        const int* __restrict__ slot, const ushort_t* __restrict__ Wb,
                        const float* __restrict__ bias, void* __restrict__ outp,
                        const int* __restrict__ cnt, const int* __restrict__ sch) {
    constexpr int KR  = STAGE1 ? DMODEL : DHID;
    constexpr int NCn = STAGE1 ? DHID : DMODEL;
    constexpr int NT  = STAGE1 ? (DMODEL / 64) : (DHID / 2 / 64);   // 12 or 24 (even)

    // bijective XCD swizzle (gridDim.x == 72, 72 % 8 == 0 -> xcd*9 + bx/8)
    const int bx = blockIdx.x;
    const int tile = (bx & 7) * 9 + (bx >> 3);
    const int nT = sch[0];
    if (tile >= nT) return;
    const int ent = sch[16 + tile];
    const int e = ent >> 20, m0 = ent & 0xFFFFF;
    const int ce = cnt[e];
    const int bH = sch[2 + e];
    const int n0 = blockIdx.y * 128;
    const int kbase = STAGE1 ? 0 : (int)blockIdx.z * (DHID / 2);

    __shared__ ushort_t lds[16384];     // 32 KB: 2 x 16KB B buffers
    char* ldsB = (char*)lds;

    const int tid = threadIdx.x, lane = tid & 63, w = tid >> 6;   // 4 waves
    const int wm = w >> 1, wn = w & 1;                            // 2 x 2
    const int fr = lane & 15, fg = lane >> 4;

    // A row pointers (direct-to-register path), 4 rows per lane
    const ushort_t* aRowP[4];
#pragma unroll
    for (int mi = 0; mi < 4; ++mi) {
        int gi = min(m0 + wm * 64 + mi * 16 + fr, ce - 1);
        size_t ar = STAGE1 ? (size_t)tok[e * TOKENS + gi] : (size_t)(bH + gi);
        aRowP[mi] = Abase + ar * KR + kbase + fg * 8;
    }

    // B staging: 1024 16B-slots per buffer (ks0: 0..511, ks1: 512..1023), 4/thread
    const ushort_t* bSrc[4]; int bDst[4];
#pragma unroll
    for (int i = 0; i < 4; ++i) {
        int s = i * 256 + tid;
        int ks = s >> 9;
        int row = (s & 511) >> 2;
        int blk = (s & 3) ^ ((row >> 1) & 3);
        bSrc[i] = Wb + ((size_t)e * NCn + n0 + row) * KR + kbase + ks * 32 + blk * 8;
        bDst[i] = s * 16;
    }

    // B fragment offsets within a ks-region (swizzled)
    int bOff[4];
#pragma unroll
    for (int ni = 0; ni < 4; ++ni) {
        int row = wn * 64 + ni * 16 + fr;
        bOff[ni] = row * 64 + ((fg ^ ((row >> 1) & 3)) << 4);
    }

    f32x4 acc[4][4] = {};
    bf16x8 aC[8], aN[8];

    // prologue: stage B(0); load A(0) into aC
#pragma unroll
    for (int i = 0; i < 4; ++i) gload16(bSrc[i], ldsB + bDst[i]);
#pragma unroll
    for (int mi = 0; mi < 4; ++mi) {
        aC[mi]     = *(const bf16x8*)(aRowP[mi]);
        aC[4 + mi] = *(const bf16x8*)(aRowP[mi] + 32);
    }
    VMCNT(0);
    wg_barrier();

#pragma unroll 1
    for (int kt = 0; kt < NT; kt += 2) {
        BODY(kt, aC, aN)
        BODY(kt + 1, aN, aC)
    }

    // ---- epilogue ----
    float bv[4];
#pragma unroll
    for (int ni = 0; ni < 4; ++ni)
        bv[ni] = bias[e * NCn + n0 + wn * 64 + ni * 16 + fr];
#pragma unroll
    for (int mi = 0; mi < 4; ++mi) {
#pragma unroll
        for (int r4 = 0; r4 < 4; ++r4) {
            int gi = m0 + wm * 64 + mi * 16 + fg * 4 + r4;
            if (gi < ce) {
                if constexpr (STAGE1) {
                    size_t orow = (size_t)(bH + gi);
#pragma unroll
                    for (int ni = 0; ni < 4; ++ni) {
                        int col = n0 + wn * 64 + ni * 16 + fr;
                        float v = gelu_tanh(acc[mi][ni][r4] + bv[ni]);
                        ((ushort_t*)outp)[orow * DHID + col] =
                            __builtin_bit_cast(ushort_t, (__bf16)v);
                    }
                } else {
                    size_t orow = (size_t)blockIdx.z * 8192 + (size_t)slot[e * TOKENS + gi];
                    float badd = (blockIdx.z == 0) ? 1.f : 0.f;
#pragma unroll
                    for (int ni = 0; ni < 4; ++ni) {
                        int col = n0 + wn * 64 + ni * 16 + fr;
                        float v = acc[mi][ni][r4] + badd * bv[ni];
                        ((ushort_t*)outp)[orow * DMODEL + col] =
                            __builtin_bit_cast(ushort_t, (__bf16)v);
                    }
                }
            }
        }
    }
}

// ---------------- combine 2 slots x 2 split-K halves (bf16) + LayerNorm ----------------
__global__ void k_ln(const ushort_t* __restrict__ Y2, const float* __restrict__ wslot,
                     const float* __restrict__ g, const float* __restrict__ b,
                     float* __restrict__ out) {
    int wv = threadIdx.x >> 6, lane = threadIdx.x & 63;
    int t = blockIdx.x * 4 + wv;
    const ushort_t* r00 = Y2 + (size_t)(2 * t) * DMODEL;
    const ushort_t* r01 = Y2 + (size_t)(8192 + 2 * t) * DMODEL;
    const ushort_t* r10 = r00 + DMODEL;
    const ushort_t* r11 = r01 + DMODEL;
    float w0 = wslot[2 * t], w1 = wslot[2 * t + 1];
    float4 v[3];
    float s = 0.f, ss = 0.f;
#pragma unroll
    for (int j = 0; j < 3; ++j) {
        int base = (j * 64 + lane) * 4;
        ushort4 a0 = *(const ushort4*)(r00 + base);
        ushort4 a1 = *(const ushort4*)(r01 + base);
        ushort4 c0 = *(const ushort4*)(r10 + base);
        ushort4 c1 = *(const ushort4*)(r11 + base);
        float4 c;
        c.x = w0 * (bf2f(a0.x) + bf2f(a1.x)) + w1 * (bf2f(c0.x) + bf2f(c1.x));
        c.y = w0 * (bf2f(a0.y) + bf2f(a1.y)) + w1 * (bf2f(c0.y) + bf2f(c1.y));
        c.z = w0 * (bf2f(a0.z) + bf2f(a1.z)) + w1 * (bf2f(c0.z) + bf2f(c1.z));
        c.w = w0 * (bf2f(a0.w) + bf2f(a1.w)) + w1 * (bf2f(c0.w) + bf2f(c1.w));
        v[j] = c;
        s  += c.x + c.y + c.z + c.w;
        ss += c.x * c.x + c.y * c.y + c.z * c.z + c.w * c.w;
    }
#pragma unroll
    for (int o = 32; o > 0; o >>= 1) { s += __shfl_xor(s, o); ss += __shfl_xor(ss, o); }
    float mu = s * (1.f / 768.f);
    float var = ss * (1.f / 768.f) - mu * mu;
    float inv = rsqrtf(var + 1e-5f);
    float* row = out + (size_t)t * DMODEL;
#pragma unroll
    for (int j = 0; j < 3; ++j) {
        int base = (j * 64 + lane) * 4;
        float4 gv = *(const float4*)(g + base);
        float4 bv = *(const float4*)(b + base);
        float4 o4;
        o4.x = (v[j].x - mu) * inv * gv.x + bv.x;
        o4.y = (v[j].y - mu) * inv * gv.y + bv.y;
        o4.z = (v[j].z - mu) * inv * gv.z + bv.z;
        o4.w = (v[j].w - mu) * inv * gv.w + bv.w;
        *(float4*)(row + base) = o4;
    }
}

extern "C" void kernel_launch(void* const* d_in, const int* in_sizes, int n_in,
                              void* d_out, int out_size, void* d_ws, size_t ws_size,
                              hipStream_t stream) {
    const float* x    = (const float*)d_in[0];
    const float* Wr   = (const float*)d_in[1];
    const float* br   = (const float*)d_in[2];
    const float* W1   = (const float*)d_in[3];
    const float* b1   = (const float*)d_in[4];
    const float* W2   = (const float*)d_in[5];
    const float* b2   = (const float*)d_in[6];
    const float* ln_g = (const float*)d_in[7];
    const float* ln_b = (const float*)d_in[8];
    float* out = (float*)d_out;

    char* ws = (char*)d_ws;
    int*      cnt   = (int*)(ws + 0);                    //    32 B
    int*      sch   = (int*)(ws + 64);                   //   ~1 KB
    int*      tok   = (int*)(ws + 4096);                 //   128 KB
    int*      slot  = (int*)(ws + 135168);               //   128 KB
    float*    wslot = (float*)(ws + 266240);             //    32 KB
    ushort_t* xb    = (ushort_t*)(ws + 327680);          //  6.29 MB
    ushort_t* W1t   = (ushort_t*)(ws + 6619136);         // 37.75 MB  [e][h][d]
    ushort_t* W2t   = (ushort_t*)(ws + 44367872);        // 37.75 MB  [e][o][h]
    ushort_t* H     = (ushort_t*)(ws + 82116608);        // 50.33 MB  [8192][3072] bf16, packed
    ushort_t* Y2    = (ushort_t*)(ws + 132448256);       // 25.17 MB  [2][8192][768] bf16

    hipMemsetAsync(cnt, 0, 32, stream);

    k_transpose_cvt<<<dim3(DHID / 64, DMODEL / 64, NEXP), dim3(256), 0, stream>>>(W1, W1t, DMODEL, DHID);
    k_transpose_cvt<<<dim3(DMODEL / 64, DHID / 64, NEXP), dim3(256), 0, stream>>>(W2, W2t, DHID, DMODEL);
    k_router<<<dim3(TOKENS / 32), dim3(256), 0, stream>>>(x, Wr, br, cnt, tok, slot, wslot, xb);
    k_sched<<<dim3(1), dim3(64), 0, stream>>>(cnt, sch);

    // stage A: H[bH+gi] = gelu(X[tok] @ W1t^T + b1)    BM=BN=128, K=768
    k_gemm8<true><<<dim3(MAXT, DHID / 128, 1), dim3(256), 0, stream>>>(
        xb, tok, slot, W1t, b1, H, cnt, sch);
    // stage B: Y2[z][slot] = H @ W2t^T (+b2 if z==0)   BM=BN=128, split-K 2x1536
    k_gemm8<false><<<dim3(MAXT, DMODEL / 128, 2), dim3(256), 0, stream>>>(
        H, tok, slot, W2t, b2, Y2, cnt, sch);

    k_ln<<<dim3(TOKENS / 4), dim3(256), 0, stream>>>(Y2, wslot, ln_g, ln_b, out);
}

// Round 12
// 303.337 us; speedup vs baseline: 1.0373x; 1.0373x over previous
//
#include <hip/hip_runtime.h>
#include <hip/hip_bf16.h>

#define TOKENS 4096
#define DMODEL 768
#define DHID   3072
#define NEXP   8
#define MAXT   72     // sum ceil(ce/128) <= 8192/128 + 7 = 71

typedef __bf16 bf16x8 __attribute__((ext_vector_type(8)));
typedef float  f32x4  __attribute__((ext_vector_type(4)));
typedef unsigned short ushort_t;

#define VMCNT(n) asm volatile("s_waitcnt vmcnt(" #n ")" ::: "memory")

__device__ __forceinline__ void wg_barrier() {
    asm volatile("" ::: "memory");
    __builtin_amdgcn_s_barrier();
    asm volatile("" ::: "memory");
}

__device__ __forceinline__ float gelu_tanh(float x) {
    // jax.nn.gelu default (approximate=True)
    float z = 0.7978845608028654f * (x + 0.044715f * x * x * x);
    float t = 1.0f - 2.0f / (__expf(2.0f * z) + 1.0f);
    return 0.5f * x * (1.0f + t);
}

__device__ __forceinline__ float bf2f(ushort_t u) {
    unsigned v = ((unsigned)u) << 16;
    return __builtin_bit_cast(float, v);
}

__device__ __forceinline__ void gload16(const void* g, void* l) {
    __builtin_amdgcn_global_load_lds((const __attribute__((address_space(1))) void*)g,
                                     (__attribute__((address_space(3))) void*)l, 16, 0, 0);
}

// ---------------- transpose + convert: in fp32 [R][C] -> out bf16 [C][R] ----------------
__global__ void k_transpose_cvt(const float* __restrict__ in, ushort_t* __restrict__ out,
                                int R, int C) {
    __shared__ float tile[64 * 68];
    const int bx = blockIdx.x, by = blockIdx.y, bz = blockIdx.z;
    const float* ip = in + (size_t)bz * R * C;
    ushort_t* op = out + (size_t)bz * R * C;
    const int tid = threadIdx.x;
    {
        const int cq = tid & 15, rg = tid >> 4;
#pragma unroll
        for (int i = 0; i < 4; ++i) {
            int rl = rg + i * 16;
            float4 v = *(const float4*)(ip + (size_t)(by * 64 + rl) * C + bx * 64 + cq * 4);
            *(float4*)(&tile[rl * 68 + cq * 4]) = v;
        }
    }
    __syncthreads();
    {
        const int rq = tid & 15, cg = tid >> 4;
#pragma unroll
        for (int i = 0; i < 4; ++i) {
            int cl = cg + i * 16;
            ushort4 o;
            o.x = __builtin_bit_cast(ushort_t, (__bf16)tile[(rq * 4 + 0) * 68 + cl]);
            o.y = __builtin_bit_cast(ushort_t, (__bf16)tile[(rq * 4 + 1) * 68 + cl]);
            o.z = __builtin_bit_cast(ushort_t, (__bf16)tile[(rq * 4 + 2) * 68 + cl]);
            o.w = __builtin_bit_cast(ushort_t, (__bf16)tile[(rq * 4 + 3) * 68 + cl]);
            *(ushort4*)(op + (size_t)(bx * 64 + cl) * R + by * 64 + rq * 4) = o;
        }
    }
}

// ---------------- router: LDS-transposed Wr, 8 tokens/wave, block-aggregated atomics ----------------
__launch_bounds__(256)
__global__ void k_router(const float* __restrict__ x, const float* __restrict__ Wr,
                         const float* __restrict__ br, int* __restrict__ cnt,
                         int* __restrict__ tok, int* __restrict__ slot,
                         float* __restrict__ wslot, ushort_t* __restrict__ xb) {
    __shared__ float WrT[NEXP * DMODEL];
    __shared__ int   te0[32], te1[32];
    __shared__ int   lcnt[NEXP], gbase[NEXP];

    const int tid = threadIdx.x;
    const int wv = tid >> 6, lane = tid & 63;

#pragma unroll
    for (int i = 0; i < 6; ++i) {
        int idx4 = i * 256 + tid;
        float4 v = ((const float4*)Wr)[idx4];
        int flat = idx4 * 4;
        int d = flat >> 3, e0 = flat & 7;
        WrT[(e0 + 0) * DMODEL + d] = v.x;
        WrT[(e0 + 1) * DMODEL + d] = v.y;
        WrT[(e0 + 2) * DMODEL + d] = v.z;
        WrT[(e0 + 3) * DMODEL + d] = v.w;
    }
    if (tid < NEXP) lcnt[tid] = 0;
    float brv[8];
#pragma unroll
    for (int e = 0; e < 8; ++e) brv[e] = br[e];
    __syncthreads();

#pragma unroll 1
    for (int it = 0; it < 8; ++it) {
        int t = blockIdx.x * 32 + wv * 8 + it;
        const float* xr = x + (size_t)t * DMODEL;
        float4 xv[3];
#pragma unroll
        for (int j = 0; j < 3; ++j) xv[j] = *(const float4*)(xr + (j * 64 + lane) * 4);
#pragma unroll
        for (int j = 0; j < 3; ++j) {
            int base = (j * 64 + lane) * 4;
            ushort4 o;
            o.x = __builtin_bit_cast(ushort_t, (__bf16)xv[j].x);
            o.y = __builtin_bit_cast(ushort_t, (__bf16)xv[j].y);
            o.z = __builtin_bit_cast(ushort_t, (__bf16)xv[j].z);
            o.w = __builtin_bit_cast(ushort_t, (__bf16)xv[j].w);
            *(ushort4*)(xb + (size_t)t * DMODEL + base) = o;
        }
        float lg[8];
#pragma unroll
        for (int e = 0; e < 8; ++e) {
            float s = 0.f;
#pragma unroll
            for (int j = 0; j < 3; ++j) {
                const float4 wv4 = *(const float4*)(&WrT[e * DMODEL + (j * 64 + lane) * 4]);
                s += xv[j].x * wv4.x;
                s += xv[j].y * wv4.y;
                s += xv[j].z * wv4.z;
                s += xv[j].w * wv4.w;
            }
#pragma unroll
            for (int o = 32; o > 0; o >>= 1) s += __shfl_xor(s, o);
            lg[e] = s + brv[e];
        }
        if (lane == 0) {
            int e0 = 0; float b0 = lg[0];
#pragma unroll
            for (int e = 1; e < 8; ++e) if (lg[e] > b0) { b0 = lg[e]; e0 = e; }
            int e1 = -1; float b1v = -1e30f;
#pragma unroll
            for (int e = 0; e < 8; ++e) if (e != e0 && lg[e] > b1v) { b1v = lg[e]; e1 = e; }
            float w0 = 1.f / (1.f + __expf(b1v - b0));
            float w1 = 1.f - w0;
            int lt = wv * 8 + it;
            te0[lt] = e0; te1[lt] = e1;
            wslot[2 * t] = w0; wslot[2 * t + 1] = w1;
        }
    }
    __syncthreads();

    int myE = 0, myPos = 0, myTok = 0, myK = 0;
    if (tid < 64) {
        int lt = tid >> 1; myK = tid & 1;
        myE = myK ? te1[lt] : te0[lt];
        myTok = blockIdx.x * 32 + lt;
        myPos = atomicAdd(&lcnt[myE], 1);
    }
    __syncthreads();
    if (tid < NEXP) gbase[tid] = atomicAdd(&cnt[tid], lcnt[tid]);
    __syncthreads();
    if (tid < 64) {
        int g = gbase[myE] + myPos;
        tok[myE * TOKENS + g] = myTok;
        slot[myE * TOKENS + g] = 2 * myTok + myK;
    }
}

// ---------------- tile scheduler: single BM=128 table ----------------
__global__ void k_sched(const int* __restrict__ cnt, int* __restrict__ sch) {
    if (threadIdx.x == 0) {
        int base = 0, n = 0;
        for (int e = 0; e < NEXP; ++e) {
            sch[2 + e] = base;
            int ce = cnt[e];
            for (int m = 0; m < ce; m += 128) sch[16 + n++] = (e << 20) | m;
            base += ce;
        }
        sch[0] = n;
    }
}

// ---------------- 128x128 GEMM: A direct global->VGPR (reg dbuf), B in swizzled LDS ----
// 4 waves (2x2), wave 64x64, BK=64, B dbuf 2x16KB, COUNTED VMCNT(8) + 1 barrier/K-tile,
// 2 blocks/CU. Per BODY, VMEM issue order: 4 gload_lds(B,kt+1) then 8 A-loads(kt+1)->AN.
// VMCNT(8) at tile end = FIFO guarantee that the 4 B-gloads landed (needed by next
// tile's ds_reads after the barrier) while the 8 A-reg-loads stay IN FLIGHT; the
// compiler's dataflow waitcnt covers AN's first use one tile later (~600cy cover).

#define BODY(kt_, AC, AN)                                                              \
    {                                                                                  \
        char* bufc = ldsB + ((kt_) & 1) * 16384;                                       \
        if ((kt_) + 1 < NT) {                                                          \
            char* bufn = ldsB + (((kt_) + 1) & 1) * 16384;                             \
            _Pragma("unroll")                                                          \
            for (int i_ = 0; i_ < 4; ++i_)                                             \
                gload16(bSrc[i_] + ((kt_) + 1) * 64, bufn + bDst[i_]);                 \
            _Pragma("unroll")                                                          \
            for (int mi_ = 0; mi_ < 4; ++mi_) {                                        \
                AN[mi_]     = *(const bf16x8*)(aRowP[mi_] + ((kt_) + 1) * 64);         \
                AN[4 + mi_] = *(const bf16x8*)(aRowP[mi_] + ((kt_) + 1) * 64 + 32);    \
            }                                                                          \
        }                                                                              \
        bf16x8 bf0[4], bf1[4];                                                         \
        _Pragma("unroll")                                                              \
        for (int ni_ = 0; ni_ < 4; ++ni_) {                                            \
            bf0[ni_] = *(const bf16x8*)(bufc + bOff[ni_]);                             \
            bf1[ni_] = *(const bf16x8*)(bufc + 8192 + bOff[ni_]);                      \
        }                                                                              \
        __builtin_amdgcn_s_setprio(1);                                                 \
        _Pragma("unroll")                                                              \
        for (int mi_ = 0; mi_ < 4; ++mi_) {                                            \
            _Pragma("unroll")                                                          \
            for (int ni_ = 0; ni_ < 4; ++ni_) {                                        \
                acc[mi_][ni_] = __builtin_amdgcn_mfma_f32_16x16x32_bf16(AC[mi_], bf0[ni_], acc[mi_][ni_], 0, 0, 0); \
                acc[mi_][ni_] = __builtin_amdgcn_mfma_f32_16x16x32_bf16(AC[4 + mi_], bf1[ni_], acc[mi_][ni_], 0, 0, 0); \
            }                                                                          \
        }                                                                              \
        __builtin_amdgcn_s_setprio(0);                                                 \
        VMCNT(8);                                                                      \
        wg_barrier();                                                                  \
    }

template<bool STAGE1>
__launch_bounds__(256, 2)
__global__ void k_gemm8(const ushort_t* __restrict__ Abase, const int* __restrict__ tok,
                        const int* __restrict__ slot, const ushort_t* __restrict__ Wb,
                        const float* __restrict__ bias, void* __restrict__ outp,
                        const int* __restrict__ cnt, const int* __restrict__ sch) {
    constexpr int KR  = STAGE1 ? DMODEL : DHID;
    constexpr int NCn = STAGE1 ? DHID : DMODEL;
    constexpr int NT  = STAGE1 ? (DMODEL / 64) : (DHID / 2 / 64);   // 12 or 24 (even)

    // bijective XCD swizzle (gridDim.x == 72, 72 % 8 == 0 -> xcd*9 + bx/8)
    const int bx = blockIdx.x;
    const int tile = (bx & 7) * 9 + (bx >> 3);
    const int nT = sch[0];
    if (tile >= nT) return;
    const int ent = sch[16 + tile];
    const int e = ent >> 20, m0 = ent & 0xFFFFF;
    const int ce = cnt[e];
    const int bH = sch[2 + e];
    const int n0 = blockIdx.y * 128;
    const int kbase = STAGE1 ? 0 : (int)blockIdx.z * (DHID / 2);

    __shared__ ushort_t lds[16384];     // 32 KB: 2 x 16KB B buffers
    char* ldsB = (char*)lds;

    const int tid = threadIdx.x, lane = tid & 63, w = tid >> 6;   // 4 waves
    const int wm = w >> 1, wn = w & 1;                            // 2 x 2
    const int fr = lane & 15, fg = lane >> 4;

    // A row pointers (direct-to-register path), 4 rows per lane
    const ushort_t* aRowP[4];
#pragma unroll
    for (int mi = 0; mi < 4; ++mi) {
        int gi = min(m0 + wm * 64 + mi * 16 + fr, ce - 1);
        size_t ar = STAGE1 ? (size_t)tok[e * TOKENS + gi] : (size_t)(bH + gi);
        aRowP[mi] = Abase + ar * KR + kbase + fg * 8;
    }

    // B staging: 1024 16B-slots per buffer (ks0: 0..511, ks1: 512..1023), 4/thread
    const ushort_t* bSrc[4]; int bDst[4];
#pragma unroll
    for (int i = 0; i < 4; ++i) {
        int s = i * 256 + tid;
        int ks = s >> 9;
        int row = (s & 511) >> 2;
        int blk = (s & 3) ^ ((row >> 1) & 3);
        bSrc[i] = Wb + ((size_t)e * NCn + n0 + row) * KR + kbase + ks * 32 + blk * 8;
        bDst[i] = s * 16;
    }

    // B fragment offsets within a ks-region (swizzled)
    int bOff[4];
#pragma unroll
    for (int ni = 0; ni < 4; ++ni) {
        int row = wn * 64 + ni * 16 + fr;
        bOff[ni] = row * 64 + ((fg ^ ((row >> 1) & 3)) << 4);
    }

    f32x4 acc[4][4] = {};
    bf16x8 aC[8], aN[8];

    // prologue: stage B(0); load A(0) into aC; counted wait (B landed, A in flight)
#pragma unroll
    for (int i = 0; i < 4; ++i) gload16(bSrc[i], ldsB + bDst[i]);
#pragma unroll
    for (int mi = 0; mi < 4; ++mi) {
        aC[mi]     = *(const bf16x8*)(aRowP[mi]);
        aC[4 + mi] = *(const bf16x8*)(aRowP[mi] + 32);
    }
    VMCNT(8);
    wg_barrier();

#pragma unroll 1
    for (int kt = 0; kt < NT; kt += 2) {
        BODY(kt, aC, aN)
        BODY(kt + 1, aN, aC)
    }

    // ---- epilogue ----
    float bv[4];
#pragma unroll
    for (int ni = 0; ni < 4; ++ni)
        bv[ni] = bias[e * NCn + n0 + wn * 64 + ni * 16 + fr];
#pragma unroll
    for (int mi = 0; mi < 4; ++mi) {
#pragma unroll
        for (int r4 = 0; r4 < 4; ++r4) {
            int gi = m0 + wm * 64 + mi * 16 + fg * 4 + r4;
            if (gi < ce) {
                if constexpr (STAGE1) {
                    size_t orow = (size_t)(bH + gi);
#pragma unroll
                    for (int ni = 0; ni < 4; ++ni) {
                        int col = n0 + wn * 64 + ni * 16 + fr;
                        float v = gelu_tanh(acc[mi][ni][r4] + bv[ni]);
                        ((ushort_t*)outp)[orow * DHID + col] =
                            __builtin_bit_cast(ushort_t, (__bf16)v);
                    }
                } else {
                    size_t orow = (size_t)blockIdx.z * 8192 + (size_t)slot[e * TOKENS + gi];
                    float badd = (blockIdx.z == 0) ? 1.f : 0.f;
#pragma unroll
                    for (int ni = 0; ni < 4; ++ni) {
                        int col = n0 + wn * 64 + ni * 16 + fr;
                        float v = acc[mi][ni][r4] + badd * bv[ni];
                        ((ushort_t*)outp)[orow * DMODEL + col] =
                            __builtin_bit_cast(ushort_t, (__bf16)v);
                    }
                }
            }
        }
    }
}

// ---------------- combine 2 slots x 2 split-K halves (bf16) + LayerNorm ----------------
__global__ void k_ln(const ushort_t* __restrict__ Y2, const float* __restrict__ wslot,
                     const float* __restrict__ g, const float* __restrict__ b,
                     float* __restrict__ out) {
    int wv = threadIdx.x >> 6, lane = threadIdx.x & 63;
    int t = blockIdx.x * 4 + wv;
    const ushort_t* r00 = Y2 + (size_t)(2 * t) * DMODEL;
    const ushort_t* r01 = Y2 + (size_t)(8192 + 2 * t) * DMODEL;
    const ushort_t* r10 = r00 + DMODEL;
    const ushort_t* r11 = r01 + DMODEL;
    float w0 = wslot[2 * t], w1 = wslot[2 * t + 1];
    float4 v[3];
    float s = 0.f, ss = 0.f;
#pragma unroll
    for (int j = 0; j < 3; ++j) {
        int base = (j * 64 + lane) * 4;
        ushort4 a0 = *(const ushort4*)(r00 + base);
        ushort4 a1 = *(const ushort4*)(r01 + base);
        ushort4 c0 = *(const ushort4*)(r10 + base);
        ushort4 c1 = *(const ushort4*)(r11 + base);
        float4 c;
        c.x = w0 * (bf2f(a0.x) + bf2f(a1.x)) + w1 * (bf2f(c0.x) + bf2f(c1.x));
        c.y = w0 * (bf2f(a0.y) + bf2f(a1.y)) + w1 * (bf2f(c0.y) + bf2f(c1.y));
        c.z = w0 * (bf2f(a0.z) + bf2f(a1.z)) + w1 * (bf2f(c0.z) + bf2f(c1.z));
        c.w = w0 * (bf2f(a0.w) + bf2f(a1.w)) + w1 * (bf2f(c0.w) + bf2f(c1.w));
        v[j] = c;
        s  += c.x + c.y + c.z + c.w;
        ss += c.x * c.x + c.y * c.y + c.z * c.z + c.w * c.w;
    }
#pragma unroll
    for (int o = 32; o > 0; o >>= 1) { s += __shfl_xor(s, o); ss += __shfl_xor(ss, o); }
    float mu = s * (1.f / 768.f);
    float var = ss * (1.f / 768.f) - mu * mu;
    float inv = rsqrtf(var + 1e-5f);
    float* row = out + (size_t)t * DMODEL;
#pragma unroll
    for (int j = 0; j < 3; ++j) {
        int base = (j * 64 + lane) * 4;
        float4 gv = *(const float4*)(g + base);
        float4 bv = *(const float4*)(b + base);
        float4 o4;
        o4.x = (v[j].x - mu) * inv * gv.x + bv.x;
        o4.y = (v[j].y - mu) * inv * gv.y + bv.y;
        o4.z = (v[j].z - mu) * inv * gv.z + bv.z;
        o4.w = (v[j].w - mu) * inv * gv.w + bv.w;
        *(float4*)(row + base) = o4;
    }
}

extern "C" void kernel_launch(void* const* d_in, const int* in_sizes, int n_in,
                              void* d_out, int out_size, void* d_ws, size_t ws_size,
                              hipStream_t stream) {
    const float* x    = (const float*)d_in[0];
    const float* Wr   = (const float*)d_in[1];
    const float* br   = (const float*)d_in[2];
    const float* W1   = (const float*)d_in[3];
    const float* b1   = (const float*)d_in[4];
    const float* W2   = (const float*)d_in[5];
    const float* b2   = (const float*)d_in[6];
    const float* ln_g = (const float*)d_in[7];
    const float* ln_b = (const float*)d_in[8];
    float* out = (float*)d_out;

    char* ws = (char*)d_ws;
    int*      cnt   = (int*)(ws + 0);                    //    32 B
    int*      sch   = (int*)(ws + 64);                   //   ~1 KB
    int*      tok   = (int*)(ws + 4096);                 //   128 KB
    int*      slot  = (int*)(ws + 135168);               //   128 KB
    float*    wslot = (float*)(ws + 266240);             //    32 KB
    ushort_t* xb    = (ushort_t*)(ws + 327680);          //  6.29 MB
    ushort_t* W1t   = (ushort_t*)(ws + 6619136);         // 37.75 MB  [e][h][d]
    ushort_t* W2t   = (ushort_t*)(ws + 44367872);        // 37.75 MB  [e][o][h]
    ushort_t* H     = (ushort_t*)(ws + 82116608);        // 50.33 MB  [8192][3072] bf16, packed
    ushort_t* Y2    = (ushort_t*)(ws + 132448256);       // 25.17 MB  [2][8192][768] bf16

    hipMemsetAsync(cnt, 0, 32, stream);

    k_transpose_cvt<<<dim3(DHID / 64, DMODEL / 64, NEXP), dim3(256), 0, stream>>>(W1, W1t, DMODEL, DHID);
    k_transpose_cvt<<<dim3(DMODEL / 64, DHID / 64, NEXP), dim3(256), 0, stream>>>(W2, W2t, DHID, DMODEL);
    k_router<<<dim3(TOKENS / 32), dim3(256), 0, stream>>>(x, Wr, br, cnt, tok, slot, wslot, xb);
    k_sched<<<dim3(1), dim3(64), 0, stream>>>(cnt, sch);

    // stage A: H[bH+gi] = gelu(X[tok] @ W1t^T + b1)    BM=BN=128, K=768
    k_gemm8<true><<<dim3(MAXT, DHID / 128, 1), dim3(256), 0, stream>>>(
        xb, tok, slot, W1t, b1, H, cnt, sch);
    // stage B: Y2[z][slot] = H @ W2t^T (+b2 if z==0)   BM=BN=128, split-K 2x1536
    k_gemm8<false><<<dim3(MAXT, DMODEL / 128, 2), dim3(256), 0, stream>>>(
        H, tok, slot, W2t, b2, Y2, cnt, sch);

    k_ln<<<dim3(TOKENS / 4), dim3(256), 0, stream>>>(Y2, wslot, ln_g, ln_b, out);
}

// Round 13
// 206.773 us; speedup vs baseline: 1.5217x; 1.4670x over previous
//
#include <hip/hip_runtime.h>
#include <hip/hip_bf16.h>

#define TOKENS 4096
#define DMODEL 768
#define DHID   3072
#define NEXP   8
#define MAXT   40     // sum ceil(ce/256) <= 8192/256 + 7 = 39

typedef __bf16 bf16x8 __attribute__((ext_vector_type(8)));
typedef float  f32x4  __attribute__((ext_vector_type(4)));
typedef unsigned short ushort_t;

#define VMCNT(n) asm volatile("s_waitcnt vmcnt(" #n ")" ::: "memory")

__device__ __forceinline__ void wg_barrier() {
    asm volatile("" ::: "memory");
    __builtin_amdgcn_s_barrier();
    asm volatile("" ::: "memory");
}

__device__ __forceinline__ float gelu_tanh(float x) {
    // jax.nn.gelu default (approximate=True)
    float z = 0.7978845608028654f * (x + 0.044715f * x * x * x);
    float t = 1.0f - 2.0f / (__expf(2.0f * z) + 1.0f);
    return 0.5f * x * (1.0f + t);
}

__device__ __forceinline__ float bf2f(ushort_t u) {
    unsigned v = ((unsigned)u) << 16;
    return __builtin_bit_cast(float, v);
}

__device__ __forceinline__ void gload16(const void* g, void* l) {
    __builtin_amdgcn_global_load_lds((const __attribute__((address_space(1))) void*)g,
                                     (__attribute__((address_space(3))) void*)l, 16, 0, 0);
}

// ---------------- transpose + convert: in fp32 [R][C] -> out bf16 [C][R] ----------------
__global__ void k_transpose_cvt(const float* __restrict__ in, ushort_t* __restrict__ out,
                                int R, int C) {
    __shared__ float tile[64 * 68];
    const int bx = blockIdx.x, by = blockIdx.y, bz = blockIdx.z;
    const float* ip = in + (size_t)bz * R * C;
    ushort_t* op = out + (size_t)bz * R * C;
    const int tid = threadIdx.x;
    {
        const int cq = tid & 15, rg = tid >> 4;
#pragma unroll
        for (int i = 0; i < 4; ++i) {
            int rl = rg + i * 16;
            float4 v = *(const float4*)(ip + (size_t)(by * 64 + rl) * C + bx * 64 + cq * 4);
            *(float4*)(&tile[rl * 68 + cq * 4]) = v;
        }
    }
    __syncthreads();
    {
        const int rq = tid & 15, cg = tid >> 4;
#pragma unroll
        for (int i = 0; i < 4; ++i) {
            int cl = cg + i * 16;
            ushort4 o;
            o.x = __builtin_bit_cast(ushort_t, (__bf16)tile[(rq * 4 + 0) * 68 + cl]);
            o.y = __builtin_bit_cast(ushort_t, (__bf16)tile[(rq * 4 + 1) * 68 + cl]);
            o.z = __builtin_bit_cast(ushort_t, (__bf16)tile[(rq * 4 + 2) * 68 + cl]);
            o.w = __builtin_bit_cast(ushort_t, (__bf16)tile[(rq * 4 + 3) * 68 + cl]);
            *(ushort4*)(op + (size_t)(bx * 64 + cl) * R + by * 64 + rq * 4) = o;
        }
    }
}

// ---------------- router: LDS-transposed Wr, 8 tokens/wave, block-aggregated atomics ----------------
__launch_bounds__(256)
__global__ void k_router(const float* __restrict__ x, const float* __restrict__ Wr,
                         const float* __restrict__ br, int* __restrict__ cnt,
                         int* __restrict__ tok, int* __restrict__ slot,
                         float* __restrict__ wslot, ushort_t* __restrict__ xb) {
    __shared__ float WrT[NEXP * DMODEL];
    __shared__ int   te0[32], te1[32];
    __shared__ int   lcnt[NEXP], gbase[NEXP];

    const int tid = threadIdx.x;
    const int wv = tid >> 6, lane = tid & 63;

#pragma unroll
    for (int i = 0; i < 6; ++i) {
        int idx4 = i * 256 + tid;
        float4 v = ((const float4*)Wr)[idx4];
        int flat = idx4 * 4;
        int d = flat >> 3, e0 = flat & 7;
        WrT[(e0 + 0) * DMODEL + d] = v.x;
        WrT[(e0 + 1) * DMODEL + d] = v.y;
        WrT[(e0 + 2) * DMODEL + d] = v.z;
        WrT[(e0 + 3) * DMODEL + d] = v.w;
    }
    if (tid < NEXP) lcnt[tid] = 0;
    float brv[8];
#pragma unroll
    for (int e = 0; e < 8; ++e) brv[e] = br[e];
    __syncthreads();

#pragma unroll 1
    for (int it = 0; it < 8; ++it) {
        int t = blockIdx.x * 32 + wv * 8 + it;
        const float* xr = x + (size_t)t * DMODEL;
        float4 xv[3];
#pragma unroll
        for (int j = 0; j < 3; ++j) xv[j] = *(const float4*)(xr + (j * 64 + lane) * 4);
#pragma unroll
        for (int j = 0; j < 3; ++j) {
            int base = (j * 64 + lane) * 4;
            ushort4 o;
            o.x = __builtin_bit_cast(ushort_t, (__bf16)xv[j].x);
            o.y = __builtin_bit_cast(ushort_t, (__bf16)xv[j].y);
            o.z = __builtin_bit_cast(ushort_t, (__bf16)xv[j].z);
            o.w = __builtin_bit_cast(ushort_t, (__bf16)xv[j].w);
            *(ushort4*)(xb + (size_t)t * DMODEL + base) = o;
        }
        float lg[8];
#pragma unroll
        for (int e = 0; e < 8; ++e) {
            float s = 0.f;
#pragma unroll
            for (int j = 0; j < 3; ++j) {
                const float4 wv4 = *(const float4*)(&WrT[e * DMODEL + (j * 64 + lane) * 4]);
                s += xv[j].x * wv4.x;
                s += xv[j].y * wv4.y;
                s += xv[j].z * wv4.z;
                s += xv[j].w * wv4.w;
            }
#pragma unroll
            for (int o = 32; o > 0; o >>= 1) s += __shfl_xor(s, o);
            lg[e] = s + brv[e];
        }
        if (lane == 0) {
            int e0 = 0; float b0 = lg[0];
#pragma unroll
            for (int e = 1; e < 8; ++e) if (lg[e] > b0) { b0 = lg[e]; e0 = e; }
            int e1 = -1; float b1v = -1e30f;
#pragma unroll
            for (int e = 0; e < 8; ++e) if (e != e0 && lg[e] > b1v) { b1v = lg[e]; e1 = e; }
            float w0 = 1.f / (1.f + __expf(b1v - b0));
            float w1 = 1.f - w0;
            int lt = wv * 8 + it;
            te0[lt] = e0; te1[lt] = e1;
            wslot[2 * t] = w0; wslot[2 * t + 1] = w1;
        }
    }
    __syncthreads();

    int myE = 0, myPos = 0, myTok = 0, myK = 0;
    if (tid < 64) {
        int lt = tid >> 1; myK = tid & 1;
        myE = myK ? te1[lt] : te0[lt];
        myTok = blockIdx.x * 32 + lt;
        myPos = atomicAdd(&lcnt[myE], 1);
    }
    __syncthreads();
    if (tid < NEXP) gbase[tid] = atomicAdd(&cnt[tid], lcnt[tid]);
    __syncthreads();
    if (tid < 64) {
        int g = gbase[myE] + myPos;
        tok[myE * TOKENS + g] = myTok;
        slot[myE * TOKENS + g] = 2 * myTok + myK;
    }
}

// ---------------- tile scheduler: single BM=256 table ----------------
__global__ void k_sched(const int* __restrict__ cnt, int* __restrict__ sch) {
    if (threadIdx.x == 0) {
        int base = 0, n = 0;
        for (int e = 0; e < NEXP; ++e) {
            sch[2 + e] = base;
            int ce = cnt[e];
            for (int m = 0; m < ce; m += 256) sch[16 + n++] = (e << 20) | m;
            base += ce;
        }
        sch[0] = n;
    }
}

// ---------------- 8-phase GEMM, m201-faithful vmcnt placement ----------------
// BM=BN=256, BK=64, 8 waves (2Mx4N), wave out 128x64, dbuf 2x64KB.
// Buffer: [A@ks0 16K][A@ks1 16K][B@ks0 16K][B@ks1 16K]; 64B rows,
//   16B blk ^= (row>>1)&3 (both-sides swizzle, measured 0 conflicts).
// Phase: ds-reads | stage 1 half-tile | (vmcnt(6) ONLY at j3 - once per K-tile,
//   per m201 template; per-phase draining was r10's -15% mistake) | barrier |
//   setprio(1) 16 MFMA setprio(0) | barrier.
// Stage schedule: (kt,j0)->A1(kt+1); (kt,j1/j2/j3)->B0/A0/B1(kt+2).
// FIFO audit: vmcnt(6)@(kt,j3) lands ALL of tile kt+1 (leaves kt+2's 3 staged
// halves in flight); consumption lag 4-7 phases, no intermediate forced drain.
// VMCNT(0) at (NT-2,j3) closes the tail.

#define STAGEH(h, t)                                                                   \
    {                                                                                  \
        const int _ks = (h) & 1, _b = (h) >> 1;                                        \
        const ushort_t* _s0 = (_b ? bSrc[0] : aSrc[0]) + (t) * 64 + _ks * 32;          \
        const ushort_t* _s1 = (_b ? bSrc[1] : aSrc[1]) + (t) * 64 + _ks * 32;          \
        char* _d = ldsB + ((t) & 1) * 65536 + _b * 32768 + _ks * 16384;                \
        gload16(_s0, _d + tid * 16);                                                   \
        gload16(_s1, _d + 8192 + tid * 16);                                            \
    }

#define PHASE(kt, J, KS, MH, LASTT)                                                    \
    {                                                                                  \
        const char* bufc = ldsB + ((kt) & 1) * 65536;                                  \
        bf16x8 af[4];                                                                  \
        _Pragma("unroll")                                                              \
        for (int _m = 0; _m < 4; ++_m)                                                 \
            af[_m] = *(const bf16x8*)(bufc + (KS) * 16384 + aoff[(MH) * 4 + _m]);      \
        if ((MH) == 0) {                                                               \
            _Pragma("unroll")                                                          \
            for (int _n = 0; _n < 4; ++_n)                                             \
                bcur[_n] = *(const bf16x8*)(bufc + 32768 + (KS) * 16384 + boff[_n]);   \
        }                                                                              \
        if ((J) == 0) { if ((kt) >= 1 && (kt) + 1 < NT) STAGEH(1, (kt) + 1) }          \
        else if ((J) == 1) { if ((kt) + 2 < NT) STAGEH(2, (kt) + 2) }                  \
        else if ((J) == 2) { if ((kt) + 2 < NT) STAGEH(0, (kt) + 2) }                  \
        else               { if ((kt) + 2 < NT) STAGEH(3, (kt) + 2) }                  \
        if ((J) == 3) {                                                                \
            if (LASTT) { VMCNT(0); } else { VMCNT(6); }                                \
        }                                                                              \
        wg_barrier();                                                                  \
        __builtin_amdgcn_s_setprio(1);                                                 \
        _Pragma("unroll")                                                              \
        for (int _m = 0; _m < 4; ++_m) {                                               \
            _Pragma("unroll")                                                          \
            for (int _n = 0; _n < 4; ++_n)                                             \
                acc[(MH) * 4 + _m][_n] = __builtin_amdgcn_mfma_f32_16x16x32_bf16(      \
                    af[_m], bcur[_n], acc[(MH) * 4 + _m][_n], 0, 0, 0);                \
        }                                                                              \
        __builtin_amdgcn_s_setprio(0);                                                 \
        wg_barrier();                                                                  \
    }

template<bool STAGE1>
__launch_bounds__(512, 1)
__global__ void k_gemm8(const ushort_t* __restrict__ Abase, const int* __restrict__ tok,
                        const int* __restrict__ slot, const ushort_t* __restrict__ Wb,
                        const float* __restrict__ bias, void* __restrict__ outp,
                        const int* __restrict__ cnt, const int* __restrict__ sch) {
    constexpr int KR  = STAGE1 ? DMODEL : DHID;
    constexpr int NCn = STAGE1 ? DHID : DMODEL;
    constexpr int NT  = STAGE1 ? (DMODEL / 64) : (DHID / 2 / 64);   // 12 or 24

    // bijective XCD swizzle (gridDim.x == 40, 40 % 8 == 0 -> xcd*5 + bx/8)
    const int bx = blockIdx.x;
    const int tile = (bx & 7) * 5 + (bx >> 3);
    const int nT = sch[0];
    if (tile >= nT) return;
    const int ent = sch[16 + tile];
    const int e = ent >> 20, m0 = ent & 0xFFFFF;
    const int ce = cnt[e];
    const int bH = sch[2 + e];
    const int n0 = blockIdx.y * 256;
    const int kbase = STAGE1 ? 0 : (int)blockIdx.z * (DHID / 2);

    __shared__ ushort_t lds[65536];     // 128 KB: 2 x 64KB buffers
    char* ldsB = (char*)lds;

    const int tid = threadIdx.x, lane = tid & 63, w = tid >> 6;   // 8 waves
    const int wm = w >> 2, wn = w & 3;                            // 2M x 4N
    const int fr = lane & 15, fg = lane >> 4;

    // staging source pointers: slots s = tid and 512+tid; row = s>>2 (0..255),
    // blk = (s&3) ^ ((row>>1)&3)  (inverse swizzle)
    const ushort_t* aSrc[2];
    const ushort_t* bSrc[2];
#pragma unroll
    for (int i = 0; i < 2; ++i) {
        int s = i * 512 + tid;
        int row = s >> 2;
        int blk = (s & 3) ^ ((row >> 1) & 3);
        int gi = min(m0 + row, ce - 1);
        size_t ar = STAGE1 ? (size_t)tok[e * TOKENS + gi] : (size_t)(bH + gi);
        aSrc[i] = Abase + ar * KR + kbase + blk * 8;
        bSrc[i] = Wb + ((size_t)e * NCn + n0 + row) * KR + kbase + blk * 8;
    }

    // fragment offsets within a ks-region (swizzled)
    int aoff[8], boff[4];
#pragma unroll
    for (int mi = 0; mi < 8; ++mi) {
        int row = wm * 128 + mi * 16 + fr;
        aoff[mi] = row * 64 + ((fg ^ ((row >> 1) & 3)) << 4);
    }
#pragma unroll
    for (int ni = 0; ni < 4; ++ni) {
        int row = wn * 64 + ni * 16 + fr;
        boff[ni] = row * 64 + ((fg ^ ((row >> 1) & 3)) << 4);
    }

    f32x4 acc[8][4] = {};
    bf16x8 bcur[4];

    // prologue: tiles 0 and 1 fully staged (8 half-tiles, 16 loads/thread);
    // VMCNT(6) lands tile0 entirely (+ tile1 A@ks0), leaves 3 halves in flight
#pragma unroll
    for (int h = 0; h < 4; ++h) STAGEH(h, 0)
#pragma unroll
    for (int h = 0; h < 4; ++h) STAGEH(h, 1)
    VMCNT(6);
    wg_barrier();

#pragma unroll 1
    for (int kt = 0; kt < NT; ++kt) {
        const bool lastt = (kt == NT - 2);
        PHASE(kt, 0, 0, 0, lastt)
        PHASE(kt, 1, 0, 1, lastt)
        PHASE(kt, 2, 1, 0, lastt)
        PHASE(kt, 3, 1, 1, lastt)
    }

    // ---- epilogue ----
    float bv[4];
#pragma unroll
    for (int ni = 0; ni < 4; ++ni)
        bv[ni] = bias[e * NCn + n0 + wn * 64 + ni * 16 + fr];
#pragma unroll
    for (int mi = 0; mi < 8; ++mi) {
#pragma unroll
        for (int r4 = 0; r4 < 4; ++r4) {
            int gi = m0 + wm * 128 + mi * 16 + fg * 4 + r4;
            if (gi < ce) {
                if constexpr (STAGE1) {
                    size_t orow = (size_t)(bH + gi);
#pragma unroll
                    for (int ni = 0; ni < 4; ++ni) {
                        int col = n0 + wn * 64 + ni * 16 + fr;
                        float v = gelu_tanh(acc[mi][ni][r4] + bv[ni]);
                        ((ushort_t*)outp)[orow * DHID + col] =
                            __builtin_bit_cast(ushort_t, (__bf16)v);
                    }
                } else {
                    size_t orow = (size_t)blockIdx.z * 8192 + (size_t)slot[e * TOKENS + gi];
                    float badd = (blockIdx.z == 0) ? 1.f : 0.f;
#pragma unroll
                    for (int ni = 0; ni < 4; ++ni) {
                        int col = n0 + wn * 64 + ni * 16 + fr;
                        float v = acc[mi][ni][r4] + badd * bv[ni];
                        ((ushort_t*)outp)[orow * DMODEL + col] =
                            __builtin_bit_cast(ushort_t, (__bf16)v);
                    }
                }
            }
        }
    }
}

// ---------------- combine 2 slots x 2 split-K halves (bf16) + LayerNorm ----------------
__global__ void k_ln(const ushort_t* __restrict__ Y2, const float* __restrict__ wslot,
                     const float* __restrict__ g, const float* __restrict__ b,
                     float* __restrict__ out) {
    int wv = threadIdx.x >> 6, lane = threadIdx.x & 63;
    int t = blockIdx.x * 4 + wv;
    const ushort_t* r00 = Y2 + (size_t)(2 * t) * DMODEL;
    const ushort_t* r01 = Y2 + (size_t)(8192 + 2 * t) * DMODEL;
    const ushort_t* r10 = r00 + DMODEL;
    const ushort_t* r11 = r01 + DMODEL;
    float w0 = wslot[2 * t], w1 = wslot[2 * t + 1];
    float4 v[3];
    float s = 0.f, ss = 0.f;
#pragma unroll
    for (int j = 0; j < 3; ++j) {
        int base = (j * 64 + lane) * 4;
        ushort4 a0 = *(const ushort4*)(r00 + base);
        ushort4 a1 = *(const ushort4*)(r01 + base);
        ushort4 c0 = *(const ushort4*)(r10 + base);
        ushort4 c1 = *(const ushort4*)(r11 + base);
        float4 c;
        c.x = w0 * (bf2f(a0.x) + bf2f(a1.x)) + w1 * (bf2f(c0.x) + bf2f(c1.x));
        c.y = w0 * (bf2f(a0.y) + bf2f(a1.y)) + w1 * (bf2f(c0.y) + bf2f(c1.y));
        c.z = w0 * (bf2f(a0.z) + bf2f(a1.z)) + w1 * (bf2f(c0.z) + bf2f(c1.z));
        c.w = w0 * (bf2f(a0.w) + bf2f(a1.w)) + w1 * (bf2f(c0.w) + bf2f(c1.w));
        v[j] = c;
        s  += c.x + c.y + c.z + c.w;
        ss += c.x * c.x + c.y * c.y + c.z * c.z + c.w * c.w;
    }
#pragma unroll
    for (int o = 32; o > 0; o >>= 1) { s += __shfl_xor(s, o); ss += __shfl_xor(ss, o); }
    float mu = s * (1.f / 768.f);
    float var = ss * (1.f / 768.f) - mu * mu;
    float inv = rsqrtf(var + 1e-5f);
    float* row = out + (size_t)t * DMODEL;
#pragma unroll
    for (int j = 0; j < 3; ++j) {
        int base = (j * 64 + lane) * 4;
        float4 gv = *(const float4*)(g + base);
        float4 bv = *(const float4*)(b + base);
        float4 o4;
        o4.x = (v[j].x - mu) * inv * gv.x + bv.x;
        o4.y = (v[j].y - mu) * inv * gv.y + bv.y;
        o4.z = (v[j].z - mu) * inv * gv.z + bv.z;
        o4.w = (v[j].w - mu) * inv * gv.w + bv.w;
        *(float4*)(row + base) = o4;
    }
}

extern "C" void kernel_launch(void* const* d_in, const int* in_sizes, int n_in,
                              void* d_out, int out_size, void* d_ws, size_t ws_size,
                              hipStream_t stream) {
    const float* x    = (const float*)d_in[0];
    const float* Wr   = (const float*)d_in[1];
    const float* br   = (const float*)d_in[2];
    const float* W1   = (const float*)d_in[3];
    const float* b1   = (const float*)d_in[4];
    const float* W2   = (const float*)d_in[5];
    const float* b2   = (const float*)d_in[6];
    const float* ln_g = (const float*)d_in[7];
    const float* ln_b = (const float*)d_in[8];
    float* out = (float*)d_out;

    char* ws = (char*)d_ws;
    int*      cnt   = (int*)(ws + 0);                    //    32 B
    int*      sch   = (int*)(ws + 64);                   //   ~1 KB
    int*      tok   = (int*)(ws + 4096);                 //   128 KB
    int*      slot  = (int*)(ws + 135168);               //   128 KB
    float*    wslot = (float*)(ws + 266240);             //    32 KB
    ushort_t* xb    = (ushort_t*)(ws + 327680);          //  6.29 MB
    ushort_t* W1t   = (ushort_t*)(ws + 6619136);         // 37.75 MB  [e][h][d]
    ushort_t* W2t   = (ushort_t*)(ws + 44367872);        // 37.75 MB  [e][o][h]
    ushort_t* H     = (ushort_t*)(ws + 82116608);        // 50.33 MB  [8192][3072] bf16, packed
    ushort_t* Y2    = (ushort_t*)(ws + 132448256);       // 25.17 MB  [2][8192][768] bf16

    hipMemsetAsync(cnt, 0, 32, stream);

    k_transpose_cvt<<<dim3(DHID / 64, DMODEL / 64, NEXP), dim3(256), 0, stream>>>(W1, W1t, DMODEL, DHID);
    k_transpose_cvt<<<dim3(DMODEL / 64, DHID / 64, NEXP), dim3(256), 0, stream>>>(W2, W2t, DHID, DMODEL);
    k_router<<<dim3(TOKENS / 32), dim3(256), 0, stream>>>(x, Wr, br, cnt, tok, slot, wslot, xb);
    k_sched<<<dim3(1), dim3(64), 0, stream>>>(cnt, sch);

    // stage A: H[bH+gi] = gelu(X[tok] @ W1t^T + b1)    BM=BN=256, K=768
    k_gemm8<true><<<dim3(MAXT, DHID / 256, 1), dim3(512), 0, stream>>>(
        xb, tok, slot, W1t, b1, H, cnt, sch);
    // stage B: Y2[z][slot] = H @ W2t^T (+b2 if z==0)   BM=BN=256, split-K 2x1536
    k_gemm8<false><<<dim3(MAXT, DMODEL / 256, 2), dim3(512), 0, stream>>>(
        H, tok, slot, W2t, b2, Y2, cnt, sch);

    k_ln<<<dim3(TOKENS / 4), dim3(256), 0, stream>>>(Y2, wslot, ln_g, ln_b, out);
}

// Round 14
// 199.862 us; speedup vs baseline: 1.5743x; 1.0346x over previous
//
#include <hip/hip_runtime.h>
#include <hip/hip_bf16.h>

#define TOKENS 4096
#define DMODEL 768
#define DHID   3072
#define NEXP   8
#define MAXT   40     // sum ceil(ce/256) <= 8192/256 + 7 = 39

typedef __bf16 bf16x8 __attribute__((ext_vector_type(8)));
typedef float  f32x4  __attribute__((ext_vector_type(4)));
typedef unsigned short ushort_t;

#define VMCNT(n) asm volatile("s_waitcnt vmcnt(" #n ")" ::: "memory")

__device__ __forceinline__ void wg_barrier() {
    asm volatile("" ::: "memory");
    __builtin_amdgcn_s_barrier();
    asm volatile("" ::: "memory");
}

__device__ __forceinline__ float gelu_tanh(float x) {
    // jax.nn.gelu default (approximate=True)
    float z = 0.7978845608028654f * (x + 0.044715f * x * x * x);
    float t = 1.0f - 2.0f / (__expf(2.0f * z) + 1.0f);
    return 0.5f * x * (1.0f + t);
}

__device__ __forceinline__ float bf2f(ushort_t u) {
    unsigned v = ((unsigned)u) << 16;
    return __builtin_bit_cast(float, v);
}

__device__ __forceinline__ void gload16(const void* g, void* l) {
    __builtin_amdgcn_global_load_lds((const __attribute__((address_space(1))) void*)g,
                                     (__attribute__((address_space(3))) void*)l, 16, 0, 0);
}

// ---------------- transpose + convert: in fp32 [R][C] -> out bf16 [C][R] ----------------
__global__ void k_transpose_cvt(const float* __restrict__ in, ushort_t* __restrict__ out,
                                int R, int C) {
    __shared__ float tile[64 * 68];
    const int bx = blockIdx.x, by = blockIdx.y, bz = blockIdx.z;
    const float* ip = in + (size_t)bz * R * C;
    ushort_t* op = out + (size_t)bz * R * C;
    const int tid = threadIdx.x;
    {
        const int cq = tid & 15, rg = tid >> 4;
#pragma unroll
        for (int i = 0; i < 4; ++i) {
            int rl = rg + i * 16;
            float4 v = *(const float4*)(ip + (size_t)(by * 64 + rl) * C + bx * 64 + cq * 4);
            *(float4*)(&tile[rl * 68 + cq * 4]) = v;
        }
    }
    __syncthreads();
    {
        const int rq = tid & 15, cg = tid >> 4;
#pragma unroll
        for (int i = 0; i < 4; ++i) {
            int cl = cg + i * 16;
            ushort4 o;
            o.x = __builtin_bit_cast(ushort_t, (__bf16)tile[(rq * 4 + 0) * 68 + cl]);
            o.y = __builtin_bit_cast(ushort_t, (__bf16)tile[(rq * 4 + 1) * 68 + cl]);
            o.z = __builtin_bit_cast(ushort_t, (__bf16)tile[(rq * 4 + 2) * 68 + cl]);
            o.w = __builtin_bit_cast(ushort_t, (__bf16)tile[(rq * 4 + 3) * 68 + cl]);
            *(ushort4*)(op + (size_t)(bx * 64 + cl) * R + by * 64 + rq * 4) = o;
        }
    }
}

// ---------------- router: LDS-transposed Wr, 8 tokens/wave, block-aggregated atomics ----------------
__launch_bounds__(256)
__global__ void k_router(const float* __restrict__ x, const float* __restrict__ Wr,
                         const float* __restrict__ br, int* __restrict__ cnt,
                         int* __restrict__ tok, int* __restrict__ slot,
                         float* __restrict__ wslot, ushort_t* __restrict__ xb) {
    __shared__ float WrT[NEXP * DMODEL];
    __shared__ int   te0[32], te1[32];
    __shared__ int   lcnt[NEXP], gbase[NEXP];

    const int tid = threadIdx.x;
    const int wv = tid >> 6, lane = tid & 63;

#pragma unroll
    for (int i = 0; i < 6; ++i) {
        int idx4 = i * 256 + tid;
        float4 v = ((const float4*)Wr)[idx4];
        int flat = idx4 * 4;
        int d = flat >> 3, e0 = flat & 7;
        WrT[(e0 + 0) * DMODEL + d] = v.x;
        WrT[(e0 + 1) * DMODEL + d] = v.y;
        WrT[(e0 + 2) * DMODEL + d] = v.z;
        WrT[(e0 + 3) * DMODEL + d] = v.w;
    }
    if (tid < NEXP) lcnt[tid] = 0;
    float brv[8];
#pragma unroll
    for (int e = 0; e < 8; ++e) brv[e] = br[e];
    __syncthreads();

#pragma unroll 1
    for (int it = 0; it < 8; ++it) {
        int t = blockIdx.x * 32 + wv * 8 + it;
        const float* xr = x + (size_t)t * DMODEL;
        float4 xv[3];
#pragma unroll
        for (int j = 0; j < 3; ++j) xv[j] = *(const float4*)(xr + (j * 64 + lane) * 4);
#pragma unroll
        for (int j = 0; j < 3; ++j) {
            int base = (j * 64 + lane) * 4;
            ushort4 o;
            o.x = __builtin_bit_cast(ushort_t, (__bf16)xv[j].x);
            o.y = __builtin_bit_cast(ushort_t, (__bf16)xv[j].y);
            o.z = __builtin_bit_cast(ushort_t, (__bf16)xv[j].z);
            o.w = __builtin_bit_cast(ushort_t, (__bf16)xv[j].w);
            *(ushort4*)(xb + (size_t)t * DMODEL + base) = o;
        }
        float lg[8];
#pragma unroll
        for (int e = 0; e < 8; ++e) {
            float s = 0.f;
#pragma unroll
            for (int j = 0; j < 3; ++j) {
                const float4 wv4 = *(const float4*)(&WrT[e * DMODEL + (j * 64 + lane) * 4]);
                s += xv[j].x * wv4.x;
                s += xv[j].y * wv4.y;
                s += xv[j].z * wv4.z;
                s += xv[j].w * wv4.w;
            }
#pragma unroll
            for (int o = 32; o > 0; o >>= 1) s += __shfl_xor(s, o);
            lg[e] = s + brv[e];
        }
        if (lane == 0) {
            int e0 = 0; float b0 = lg[0];
#pragma unroll
            for (int e = 1; e < 8; ++e) if (lg[e] > b0) { b0 = lg[e]; e0 = e; }
            int e1 = -1; float b1v = -1e30f;
#pragma unroll
            for (int e = 0; e < 8; ++e) if (e != e0 && lg[e] > b1v) { b1v = lg[e]; e1 = e; }
            float w0 = 1.f / (1.f + __expf(b1v - b0));
            float w1 = 1.f - w0;
            int lt = wv * 8 + it;
            te0[lt] = e0; te1[lt] = e1;
            wslot[2 * t] = w0; wslot[2 * t + 1] = w1;
        }
    }
    __syncthreads();

    int myE = 0, myPos = 0, myTok = 0, myK = 0;
    if (tid < 64) {
        int lt = tid >> 1; myK = tid & 1;
        myE = myK ? te1[lt] : te0[lt];
        myTok = blockIdx.x * 32 + lt;
        myPos = atomicAdd(&lcnt[myE], 1);
    }
    __syncthreads();
    if (tid < NEXP) gbase[tid] = atomicAdd(&cnt[tid], lcnt[tid]);
    __syncthreads();
    if (tid < 64) {
        int g = gbase[myE] + myPos;
        tok[myE * TOKENS + g] = myTok;
        slot[myE * TOKENS + g] = 2 * myTok + myK;
    }
}

// ---------------- tile scheduler ----------------
// sch[0]=nA(BM=128 unused here)=nT, sch[2..9]=baseH prefix, sch[16..]= tiles (e<<20|m0)
__global__ void k_sched(const int* __restrict__ cnt, int* __restrict__ sch) {
    if (threadIdx.x == 0) {
        int base = 0, n = 0;
        for (int e = 0; e < NEXP; ++e) {
            sch[2 + e] = base;
            int ce = cnt[e];
            for (int m = 0; m < ce; m += 256) sch[16 + n++] = (e << 20) | m;
            base += ce;
        }
        sch[0] = n;
    }
}

// ---------------- 4-phase/K-tile counted-vmcnt GEMM (session best: 202 µs total) ----
// BM=BN=256, BK=64, 8 waves (2x4), wave-tile 128x64, 2x64KB LDS dbuf.
// Buffer layout: [A-ks0 16K][A-ks1 16K][B-ks0 16K][B-ks1 16K]
//   region addr = row*64 + ((blk ^ ((row>>1)&3))<<4)

#define ISSUE(c, kt1, BOFF)                                                            \
    {                                                                                  \
        _Pragma("unroll")                                                              \
        for (int i_ = 0; i_ < 2; ++i_) {                                               \
            const ushort_t* s_ = (((c) & 1) ? bPtr[i_] : aPtr[i_]) + (kt1) * 64 + (((c) >> 1) * 32); \
            gload16(s_, ldsB + (BOFF) + (((c) & 1) ? 32768 : 0) + (((c) >> 1) * 16384) \
                            + w * 2048 + i_ * 1024);                                   \
        }                                                                              \
    }

#define MFMA16(NH)                                                                     \
    __builtin_amdgcn_s_setprio(1);                                                     \
    _Pragma("unroll")                                                                  \
    for (int mi = 0; mi < 8; ++mi) {                                                   \
        acc[mi][(NH)*2 + 0] = __builtin_amdgcn_mfma_f32_16x16x32_bf16(af[mi], bf[0], acc[mi][(NH)*2 + 0], 0, 0, 0); \
        acc[mi][(NH)*2 + 1] = __builtin_amdgcn_mfma_f32_16x16x32_bf16(af[mi], bf[1], acc[mi][(NH)*2 + 1], 0, 0, 0); \
    }                                                                                  \
    __builtin_amdgcn_s_setprio(0);

#define TILE(kt, BUFOFF, PF, LAST)                                                     \
    {                                                                                  \
        const char* bufL = ldsB + (BUFOFF);                                            \
        bf16x8 af[8], bf[2];                                                           \
        /* phase 0: ks0 nh0 */                                                         \
        _Pragma("unroll")                                                              \
        for (int mi = 0; mi < 8; ++mi) af[mi] = *(const bf16x8*)(bufL + abase + mi * 1024); \
        bf[0] = *(const bf16x8*)(bufL + bbase + 0 * 1024);                             \
        bf[1] = *(const bf16x8*)(bufL + bbase + 1 * 1024);                             \
        if (PF) ISSUE(0, (kt) + 1, (BUFOFF) ^ 65536);                                  \
        wg_barrier();                                                                  \
        MFMA16(0)                                                                      \
        wg_barrier();                                                                  \
        /* phase 1: ks0 nh1 */                                                         \
        bf[0] = *(const bf16x8*)(bufL + bbase + 2 * 1024);                             \
        bf[1] = *(const bf16x8*)(bufL + bbase + 3 * 1024);                             \
        if (PF) ISSUE(1, (kt) + 1, (BUFOFF) ^ 65536);                                  \
        wg_barrier();                                                                  \
        MFMA16(1)                                                                      \
        if (LAST) { VMCNT(0); } else { VMCNT(4); }                                     \
        wg_barrier();                                                                  \
        /* phase 2: ks1 nh0 */                                                         \
        _Pragma("unroll")                                                              \
        for (int mi = 0; mi < 8; ++mi) af[mi] = *(const bf16x8*)(bufL + abase + 16384 + mi * 1024); \
        bf[0] = *(const bf16x8*)(bufL + bbase + 16384 + 0 * 1024);                     \
        bf[1] = *(const bf16x8*)(bufL + bbase + 16384 + 1 * 1024);                     \
        if (PF) ISSUE(2, (kt) + 1, (BUFOFF) ^ 65536);                                  \
        wg_barrier();                                                                  \
        MFMA16(0)                                                                      \
        wg_barrier();                                                                  \
        /* phase 3: ks1 nh1 */                                                         \
        bf[0] = *(const bf16x8*)(bufL + bbase + 16384 + 2 * 1024);                     \
        bf[1] = *(const bf16x8*)(bufL + bbase + 16384 + 3 * 1024);                     \
        if (PF) ISSUE(3, (kt) + 1, (BUFOFF) ^ 65536);                                  \
        wg_barrier();                                                                  \
        MFMA16(1)                                                                      \
        VMCNT(4);                                                                      \
        wg_barrier();                                                                  \
    }

template<bool STAGE1>
__launch_bounds__(512, 1)
__global__ void k_gemm8(const ushort_t* __restrict__ Abase, const int* __restrict__ tok,
                        const int* __restrict__ slot, const ushort_t* __restrict__ Wb,
                        const float* __restrict__ bias, void* __restrict__ outp,
                        const int* __restrict__ cnt, const int* __restrict__ sch) {
    constexpr int KR  = STAGE1 ? DMODEL : DHID;
    constexpr int NCn = STAGE1 ? DHID : DMODEL;
    constexpr int NT  = STAGE1 ? (DMODEL / 64) : (DHID / 2 / 64);   // 12 or 24 (even)

    // bijective XCD swizzle (gridDim.x == 40, 40 % 8 == 0 -> xcd*5 + bx/8)
    const int bx = blockIdx.x;
    const int tile = (bx & 7) * 5 + (bx >> 3);
    const int nT = sch[0];
    if (tile >= nT) return;
    const int ent = sch[16 + tile];
    const int e = ent >> 20, m0 = ent & 0xFFFFF;
    const int ce = cnt[e];
    const int bH = sch[2 + e];
    const int n0 = blockIdx.y * 256;
    const int kbase = STAGE1 ? 0 : (int)blockIdx.z * (DHID / 2);

    __shared__ ushort_t lds[65536];     // 128 KB: 2 x 64KB buffers
    char* ldsB = (char*)lds;

    const int tid = threadIdx.x, lane = tid & 63, w = tid >> 6;
    const int wm = w >> 2, wn = w & 3;          // 2 x 4 waves
    const int wmBase = wm * 128, wnBase = wn * 64;
    const int fr = lane & 15, fg = lane >> 4;

    // staging source pointers (inverse-swizzled global columns)
    const ushort_t* aPtr[2];
    const ushort_t* bPtr[2];
#pragma unroll
    for (int i = 0; i < 2; ++i) {
        int j = w * 2 + i;
        int row = j * 16 + (lane >> 2);
        int gblk = (lane & 3) ^ ((row >> 1) & 3);
        int gi = min(m0 + row, ce - 1);
        size_t ar = STAGE1 ? (size_t)tok[e * TOKENS + gi] : (size_t)(bH + gi);
        aPtr[i] = Abase + ar * KR + kbase + gblk * 8;
        bPtr[i] = Wb + ((size_t)e * NCn + n0 + row) * KR + kbase + gblk * 8;
    }

    // ds_read base addrs (swizzle term invariant under mi*16 / ks / ni steps)
    const int arow0 = wmBase + fr;
    const int abase = arow0 * 64 + ((fg ^ ((arow0 >> 1) & 3)) << 4);
    const int brow0 = wnBase + fr;
    const int bbase = 32768 + brow0 * 64 + ((fg ^ ((brow0 >> 1) & 3)) << 4);

    f32x4 acc[8][4] = {};

    // prologue: all 4 chunks of tile 0 into buf0
    ISSUE(0, 0, 0); ISSUE(1, 0, 0); ISSUE(2, 0, 0); ISSUE(3, 0, 0);
    VMCNT(4);           // ks0 chunks of tile 0 landed; ks1 still in flight
    wg_barrier();

#pragma unroll 1
    for (int kt = 0; kt < NT - 2; kt += 2) {
        TILE(kt, 0, 1, 0)
        TILE(kt + 1, 65536, 1, 0)
    }
    TILE(NT - 2, 0, 1, 0)
    TILE(NT - 1, 65536, 0, 1)

    // ---- epilogue ----
    float bv[4];
#pragma unroll
    for (int ni = 0; ni < 4; ++ni)
        bv[ni] = bias[e * NCn + n0 + wnBase + ni * 16 + fr];
#pragma unroll
    for (int mi = 0; mi < 8; ++mi) {
#pragma unroll
        for (int r4 = 0; r4 < 4; ++r4) {
            int gi = m0 + wmBase + mi * 16 + fg * 4 + r4;
            if (gi < ce) {
                if constexpr (STAGE1) {
                    size_t orow = (size_t)(bH + gi);
#pragma unroll
                    for (int ni = 0; ni < 4; ++ni) {
                        int col = n0 + wnBase + ni * 16 + fr;
                        float v = gelu_tanh(acc[mi][ni][r4] + bv[ni]);
                        ((ushort_t*)outp)[orow * DHID + col] =
                            __builtin_bit_cast(ushort_t, (__bf16)v);
                    }
                } else {
                    size_t orow = (size_t)blockIdx.z * 8192 + (size_t)slot[e * TOKENS + gi];
                    float badd = (blockIdx.z == 0) ? 1.f : 0.f;
#pragma unroll
                    for (int ni = 0; ni < 4; ++ni) {
                        int col = n0 + wnBase + ni * 16 + fr;
                        float v = acc[mi][ni][r4] + badd * bv[ni];
                        ((ushort_t*)outp)[orow * DMODEL + col] =
                            __builtin_bit_cast(ushort_t, (__bf16)v);
                    }
                }
            }
        }
    }
}

// ---------------- combine 2 slots x 2 split-K halves (bf16) + LayerNorm ----------------
__global__ void k_ln(const ushort_t* __restrict__ Y2, const float* __restrict__ wslot,
                     const float* __restrict__ g, const float* __restrict__ b,
                     float* __restrict__ out) {
    int wv = threadIdx.x >> 6, lane = threadIdx.x & 63;
    int t = blockIdx.x * 4 + wv;
    const ushort_t* r00 = Y2 + (size_t)(2 * t) * DMODEL;
    const ushort_t* r01 = Y2 + (size_t)(8192 + 2 * t) * DMODEL;
    const ushort_t* r10 = r00 + DMODEL;
    const ushort_t* r11 = r01 + DMODEL;
    float w0 = wslot[2 * t], w1 = wslot[2 * t + 1];
    float4 v[3];
    float s = 0.f, ss = 0.f;
#pragma unroll
    for (int j = 0; j < 3; ++j) {
        int base = (j * 64 + lane) * 4;
        ushort4 a0 = *(const ushort4*)(r00 + base);
        ushort4 a1 = *(const ushort4*)(r01 + base);
        ushort4 c0 = *(const ushort4*)(r10 + base);
        ushort4 c1 = *(const ushort4*)(r11 + base);
        float4 c;
        c.x = w0 * (bf2f(a0.x) + bf2f(a1.x)) + w1 * (bf2f(c0.x) + bf2f(c1.x));
        c.y = w0 * (bf2f(a0.y) + bf2f(a1.y)) + w1 * (bf2f(c0.y) + bf2f(c1.y));
        c.z = w0 * (bf2f(a0.z) + bf2f(a1.z)) + w1 * (bf2f(c0.z) + bf2f(c1.z));
        c.w = w0 * (bf2f(a0.w) + bf2f(a1.w)) + w1 * (bf2f(c0.w) + bf2f(c1.w));
        v[j] = c;
        s  += c.x + c.y + c.z + c.w;
        ss += c.x * c.x + c.y * c.y + c.z * c.z + c.w * c.w;
    }
#pragma unroll
    for (int o = 32; o > 0; o >>= 1) { s += __shfl_xor(s, o); ss += __shfl_xor(ss, o); }
    float mu = s * (1.f / 768.f);
    float var = ss * (1.f / 768.f) - mu * mu;
    float inv = rsqrtf(var + 1e-5f);
    float* row = out + (size_t)t * DMODEL;
#pragma unroll
    for (int j = 0; j < 3; ++j) {
        int base = (j * 64 + lane) * 4;
        float4 gv = *(const float4*)(g + base);
        float4 bv = *(const float4*)(b + base);
        float4 o4;
        o4.x = (v[j].x - mu) * inv * gv.x + bv.x;
        o4.y = (v[j].y - mu) * inv * gv.y + bv.y;
        o4.z = (v[j].z - mu) * inv * gv.z + bv.z;
        o4.w = (v[j].w - mu) * inv * gv.w + bv.w;
        *(float4*)(row + base) = o4;
    }
}

extern "C" void kernel_launch(void* const* d_in, const int* in_sizes, int n_in,
                              void* d_out, int out_size, void* d_ws, size_t ws_size,
                              hipStream_t stream) {
    const float* x    = (const float*)d_in[0];
    const float* Wr   = (const float*)d_in[1];
    const float* br   = (const float*)d_in[2];
    const float* W1   = (const float*)d_in[3];
    const float* b1   = (const float*)d_in[4];
    const float* W2   = (const float*)d_in[5];
    const float* b2   = (const float*)d_in[6];
    const float* ln_g = (const float*)d_in[7];
    const float* ln_b = (const float*)d_in[8];
    float* out = (float*)d_out;

    char* ws = (char*)d_ws;
    int*      cnt   = (int*)(ws + 0);                    //    32 B
    int*      sch   = (int*)(ws + 64);                   //   ~1 KB
    int*      tok   = (int*)(ws + 4096);                 //   128 KB
    int*      slot  = (int*)(ws + 135168);               //   128 KB
    float*    wslot = (float*)(ws + 266240);             //    32 KB
    ushort_t* xb    = (ushort_t*)(ws + 327680);          //  6.29 MB
    ushort_t* W1t   = (ushort_t*)(ws + 6619136);         // 37.75 MB  [e][h][d]
    ushort_t* W2t   = (ushort_t*)(ws + 44367872);        // 37.75 MB  [e][o][h]
    ushort_t* H     = (ushort_t*)(ws + 82116608);        // 50.33 MB  [8192][3072] bf16, packed
    ushort_t* Y2    = (ushort_t*)(ws + 132448256);       // 25.17 MB  [2][8192][768] bf16

    hipMemsetAsync(cnt, 0, 32, stream);

    k_transpose_cvt<<<dim3(DHID / 64, DMODEL / 64, NEXP), dim3(256), 0, stream>>>(W1, W1t, DMODEL, DHID);
    k_transpose_cvt<<<dim3(DMODEL / 64, DHID / 64, NEXP), dim3(256), 0, stream>>>(W2, W2t, DHID, DMODEL);
    k_router<<<dim3(TOKENS / 32), dim3(256), 0, stream>>>(x, Wr, br, cnt, tok, slot, wslot, xb);
    k_sched<<<dim3(1), dim3(64), 0, stream>>>(cnt, sch);

    // stage A: H[bH+gi] = gelu(X[tok] @ W1t^T + b1)    BM=BN=256, K=768
    k_gemm8<true><<<dim3(MAXT, DHID / 256, 1), dim3(512), 0, stream>>>(
        xb, tok, slot, W1t, b1, H, cnt, sch);
    // stage B: Y2[z][slot] = H @ W2t^T (+b2 if z==0)   BM=BN=256, split-K 2x1536
    k_gemm8<false><<<dim3(MAXT, DMODEL / 256, 2), dim3(512), 0, stream>>>(
        H, tok, slot, W2t, b2, Y2, cnt, sch);

    k_ln<<<dim3(TOKENS / 4), dim3(256), 0, stream>>>(Y2, wslot, ln_g, ln_b, out);
}